// Round 1
// baseline (1167.097 us; speedup 1.0000x reference)
//
#include <hip/hip_runtime.h>

#define B_   4
#define CO   256
#define CIN  1024
#define CQ   32
#define HN   16384               // H*W pixels per image
#define NTOT ((size_t)B_ * CO * HN)

// ---------------------------------------------------------------------------
// Kernel 1: 1x1 conv as GEMM  x[b,o,n] = sum_c w[o,c] * fcat[b,c,n]
// fcat channels: [0,256)=s5, [256,512)=s4, [512,768)=s3, [768,1024)=s2
// 64x64 output tile, 256 threads, 4x4 per thread, K-tile 16.
// ---------------------------------------------------------------------------
__global__ __launch_bounds__(256) void conv_gemm(
    const float* __restrict__ s5, const float* __restrict__ s4,
    const float* __restrict__ s3, const float* __restrict__ s2,
    const float* __restrict__ w, float* __restrict__ x)
{
    __shared__ float a_s[16][64];
    __shared__ float b_s[16][64];
    const int n0  = blockIdx.x * 64;
    const int m0  = blockIdx.y * 64;
    const int b   = blockIdx.z;
    const int tid = threadIdx.x;
    const int tx  = tid % 16, ty = tid / 16;

    float acc[4][4] = {};
    for (int k0 = 0; k0 < CIN; k0 += 16) {
        // A tile: w[m0+r][k0+kk]
        #pragma unroll
        for (int i = 0; i < 4; ++i) {
            int j = tid + 256 * i;
            int kk = j & 15, r = j >> 4;
            a_s[kk][r] = w[(size_t)(m0 + r) * CIN + k0 + kk];
        }
        // B tile: fcat[k0+kk][n0+nn] (select source tensor; k-tile never straddles)
        const int t = k0 >> 8;
        const float* src = (t == 0) ? s5 : (t == 1) ? s4 : (t == 2) ? s3 : s2;
        const size_t cbase = ((size_t)b * 256 + (k0 & 255)) * HN + n0;
        #pragma unroll
        for (int i = 0; i < 4; ++i) {
            int j = tid + 256 * i;
            int nn = j & 63, kk = j >> 6;
            b_s[kk][nn] = src[cbase + (size_t)kk * HN + nn];
        }
        __syncthreads();
        #pragma unroll
        for (int kk = 0; kk < 16; ++kk) {
            float av[4], bv[4];
            #pragma unroll
            for (int i = 0; i < 4; ++i) av[i] = a_s[kk][ty * 4 + i];
            #pragma unroll
            for (int j = 0; j < 4; ++j) bv[j] = b_s[kk][tx * 4 + j];
            #pragma unroll
            for (int i = 0; i < 4; ++i)
                #pragma unroll
                for (int j = 0; j < 4; ++j) acc[i][j] += av[i] * bv[j];
        }
        __syncthreads();
    }
    #pragma unroll
    for (int i = 0; i < 4; ++i)
        #pragma unroll
        for (int j = 0; j < 4; ++j)
            x[((size_t)b * CO + m0 + ty * 4 + i) * HN + n0 + tx * 4 + j] = acc[i][j];
}

// ---------------------------------------------------------------------------
// Kernel 2: per-channel BN stats over (B, N); writes fused scale/shift
// ---------------------------------------------------------------------------
__global__ __launch_bounds__(256) void bn_stats(
    const float* __restrict__ x, const float* __restrict__ g,
    const float* __restrict__ bt, float* __restrict__ scale,
    float* __restrict__ shift)
{
    const int o = blockIdx.x;
    const int tid = threadIdx.x;
    float s = 0.f, ss = 0.f;
    for (int b = 0; b < B_; ++b) {
        const float* p = x + ((size_t)b * CO + o) * HN;
        for (int i = tid; i < HN; i += 256) { float v = p[i]; s += v; ss += v * v; }
    }
    #pragma unroll
    for (int off = 32; off; off >>= 1) {
        s += __shfl_down(s, off, 64);
        ss += __shfl_down(ss, off, 64);
    }
    __shared__ float sh[2][4];
    if ((tid & 63) == 0) { sh[0][tid >> 6] = s; sh[1][tid >> 6] = ss; }
    __syncthreads();
    if (tid == 0) {
        float S  = sh[0][0] + sh[0][1] + sh[0][2] + sh[0][3];
        float SS = sh[1][0] + sh[1][1] + sh[1][2] + sh[1][3];
        const float cnt = (float)(B_ * HN);
        float mu  = S / cnt;
        float var = SS / cnt - mu * mu;
        float sc  = g[o] * rsqrtf(var + 1e-5f);
        scale[o] = sc;
        shift[o] = bt[o] - mu * sc;
    }
}

// ---------------------------------------------------------------------------
// Kernel 3: in-place BN affine + ReLU (float4, channel constant within vec4)
// ---------------------------------------------------------------------------
__global__ __launch_bounds__(256) void bn_relu(
    float* __restrict__ x, const float* __restrict__ scale,
    const float* __restrict__ shift)
{
    size_t idx = (size_t)blockIdx.x * 256 + threadIdx.x;   // float4 index
    float4 v = ((const float4*)x)[idx];
    int o = (int)((idx * 4 / HN) % CO);
    float sc = scale[o], sf = shift[o];
    v.x = fmaxf(fmaf(v.x, sc, sf), 0.f);
    v.y = fmaxf(fmaf(v.y, sc, sf), 0.f);
    v.z = fmaxf(fmaf(v.z, sc, sf), 0.f);
    v.w = fmaxf(fmaf(v.w, sc, sf), 0.f);
    ((float4*)x)[idx] = v;
}

// ---------------------------------------------------------------------------
// Kernel 4: fused Q/K projection (64 rows = 32 Q + 32 K), per-pixel L2 norm,
// writes Qt[b][n][q] (pixel-major) and Kn[b][q][n] (channel-major).
// ---------------------------------------------------------------------------
__global__ __launch_bounds__(256) void qk_gemm(
    const float* __restrict__ feat, const float* __restrict__ wq,
    const float* __restrict__ bq, const float* __restrict__ wk,
    const float* __restrict__ bk, float* __restrict__ Qt,
    float* __restrict__ Kqn)
{
    __shared__ float a_s[16][64];
    __shared__ float b_s[16][64];
    __shared__ float o_s[64][65];
    __shared__ float invq[64], invk[64];
    const int n0  = blockIdx.x * 64;
    const int b   = blockIdx.z;
    const int tid = threadIdx.x;
    const int tx  = tid % 16, ty = tid / 16;

    float acc[4][4] = {};
    for (int k0 = 0; k0 < CO; k0 += 16) {
        #pragma unroll
        for (int i = 0; i < 4; ++i) {
            int j = tid + 256 * i;
            int kk = j & 15, r = j >> 4;
            a_s[kk][r] = (r < 32) ? wq[(size_t)r * CO + k0 + kk]
                                  : wk[(size_t)(r - 32) * CO + k0 + kk];
        }
        const size_t cbase = ((size_t)b * CO + k0) * HN + n0;
        #pragma unroll
        for (int i = 0; i < 4; ++i) {
            int j = tid + 256 * i;
            int nn = j & 63, kk = j >> 6;
            b_s[kk][nn] = feat[cbase + (size_t)kk * HN + nn];
        }
        __syncthreads();
        #pragma unroll
        for (int kk = 0; kk < 16; ++kk) {
            float av[4], bv[4];
            #pragma unroll
            for (int i = 0; i < 4; ++i) av[i] = a_s[kk][ty * 4 + i];
            #pragma unroll
            for (int j = 0; j < 4; ++j) bv[j] = b_s[kk][tx * 4 + j];
            #pragma unroll
            for (int i = 0; i < 4; ++i)
                #pragma unroll
                for (int j = 0; j < 4; ++j) acc[i][j] += av[i] * bv[j];
        }
        __syncthreads();
    }
    #pragma unroll
    for (int i = 0; i < 4; ++i)
        #pragma unroll
        for (int j = 0; j < 4; ++j) {
            int r = ty * 4 + i;
            float bias = (r < 32) ? bq[r] : bk[r - 32];
            o_s[r][tx * 4 + j] = acc[i][j] + bias;
        }
    __syncthreads();
    if (tid < 64) {
        int p = tid;
        float sq = 0.f, sk = 0.f;
        #pragma unroll
        for (int r = 0; r < 32; ++r) { float v = o_s[r][p];      sq += v * v; }
        #pragma unroll
        for (int r = 0; r < 32; ++r) { float v = o_s[32 + r][p]; sk += v * v; }
        invq[p] = 1.f / fmaxf(sqrtf(sq), 1e-6f);
        invk[p] = 1.f / fmaxf(sqrtf(sk), 1e-6f);
    }
    __syncthreads();
    // Qt[b][n0+p][q]
    #pragma unroll
    for (int i = 0; i < 8; ++i) {
        int j = tid + 256 * i;
        int q = j & 31, p = j >> 5;
        Qt[((size_t)b * HN + n0 + p) * CQ + q] = o_s[q][p] * invq[p];
    }
    // Kn[b][q][n0+p]
    #pragma unroll
    for (int i = 0; i < 8; ++i) {
        int j = tid + 256 * i;
        int p = j & 63, q = j >> 6;
        Kqn[((size_t)b * CQ + q) * HN + n0 + p] = o_s[32 + q][p] * invk[p];
    }
}

// ---------------------------------------------------------------------------
// Kernel 5: V projection  V[b,c,n] = sum_k wv[c,k] feat[b,k,n] + bv[c]
// ---------------------------------------------------------------------------
__global__ __launch_bounds__(256) void v_gemm(
    const float* __restrict__ feat, const float* __restrict__ wv,
    const float* __restrict__ bv, float* __restrict__ V)
{
    __shared__ float a_s[16][64];
    __shared__ float b_s[16][64];
    const int n0  = blockIdx.x * 64;
    const int m0  = blockIdx.y * 64;
    const int b   = blockIdx.z;
    const int tid = threadIdx.x;
    const int tx  = tid % 16, ty = tid / 16;

    float acc[4][4] = {};
    for (int k0 = 0; k0 < CO; k0 += 16) {
        #pragma unroll
        for (int i = 0; i < 4; ++i) {
            int j = tid + 256 * i;
            int kk = j & 15, r = j >> 4;
            a_s[kk][r] = wv[(size_t)(m0 + r) * CO + k0 + kk];
        }
        const size_t cbase = ((size_t)b * CO + k0) * HN + n0;
        #pragma unroll
        for (int i = 0; i < 4; ++i) {
            int j = tid + 256 * i;
            int nn = j & 63, kk = j >> 6;
            b_s[kk][nn] = feat[cbase + (size_t)kk * HN + nn];
        }
        __syncthreads();
        #pragma unroll
        for (int kk = 0; kk < 16; ++kk) {
            float av[4], bv_[4];
            #pragma unroll
            for (int i = 0; i < 4; ++i) av[i] = a_s[kk][ty * 4 + i];
            #pragma unroll
            for (int j = 0; j < 4; ++j) bv_[j] = b_s[kk][tx * 4 + j];
            #pragma unroll
            for (int i = 0; i < 4; ++i)
                #pragma unroll
                for (int j = 0; j < 4; ++j) acc[i][j] += av[i] * bv_[j];
        }
        __syncthreads();
    }
    #pragma unroll
    for (int i = 0; i < 4; ++i) {
        float bias = bv[m0 + ty * 4 + i];
        #pragma unroll
        for (int j = 0; j < 4; ++j)
            V[((size_t)b * CO + m0 + ty * 4 + i) * HN + n0 + tx * 4 + j] =
                acc[i][j] + bias;
    }
}

// ---------------------------------------------------------------------------
// Kernel 6: generic contiguous row-sum (Ksum over Kn rows, Vsum over V rows)
// ---------------------------------------------------------------------------
__global__ __launch_bounds__(256) void rowsum(
    const float* __restrict__ src, float* __restrict__ dst, int rowlen)
{
    const size_t r = blockIdx.x;
    const int tid = threadIdx.x;
    float s = 0.f;
    const float* p = src + r * (size_t)rowlen;
    for (int i = tid; i < rowlen; i += 256) s += p[i];
    #pragma unroll
    for (int off = 32; off; off >>= 1) s += __shfl_down(s, off, 64);
    __shared__ float sh[4];
    if ((tid & 63) == 0) sh[tid >> 6] = s;
    __syncthreads();
    if (tid == 0) dst[r] = sh[0] + sh[1] + sh[2] + sh[3];
}

// ---------------------------------------------------------------------------
// Kernel 7: KV outer-product partials  part[b,chunk,q,c] = sum_{n in chunk} Kn*V
// 64 chunks x 256 pixels; block accumulates full 32x256 in registers.
// ---------------------------------------------------------------------------
__global__ __launch_bounds__(256) void kv_partial(
    const float* __restrict__ Kqn, const float* __restrict__ V,
    float* __restrict__ part)
{
    __shared__ float a_s[CQ][33];       // [q][nn]
    __shared__ float v_s[32][CO + 1];   // [nn][c]
    const int chunk = blockIdx.x;
    const int b     = blockIdx.y;
    const int tid   = threadIdx.x;
    const int tc = tid & 31, tq = tid >> 5;   // c = tc + 32*ci, q = tq*4 + qi
    float acc[4][8] = {};
    const int p0 = chunk * 256;

    for (int nt = 0; nt < 8; ++nt) {
        const int pb = p0 + nt * 32;
        #pragma unroll
        for (int i = 0; i < 4; ++i) {
            int j = tid + 256 * i;
            int nn = j & 31, q = j >> 5;
            a_s[q][nn] = Kqn[((size_t)b * CQ + q) * HN + pb + nn];
        }
        #pragma unroll
        for (int i = 0; i < 32; ++i) {
            int j = tid + 256 * i;
            int nn = j & 31, c = j >> 5;
            v_s[nn][c] = V[((size_t)b * CO + c) * HN + pb + nn];
        }
        __syncthreads();
        #pragma unroll 4
        for (int nn = 0; nn < 32; ++nn) {
            float av[4], vv[8];
            #pragma unroll
            for (int qi = 0; qi < 4; ++qi) av[qi] = a_s[tq * 4 + qi][nn];
            #pragma unroll
            for (int ci = 0; ci < 8; ++ci) vv[ci] = v_s[nn][tc + 32 * ci];
            #pragma unroll
            for (int qi = 0; qi < 4; ++qi)
                #pragma unroll
                for (int ci = 0; ci < 8; ++ci) acc[qi][ci] += av[qi] * vv[ci];
        }
        __syncthreads();
    }
    float* dst = part + ((size_t)b * 64 + chunk) * CQ * CO;
    #pragma unroll
    for (int qi = 0; qi < 4; ++qi)
        #pragma unroll
        for (int ci = 0; ci < 8; ++ci)
            dst[(tq * 4 + qi) * CO + tc + 32 * ci] = acc[qi][ci];
}

// ---------------------------------------------------------------------------
// Kernel 8: reduce partials -> matrix[b,q,c]
// ---------------------------------------------------------------------------
__global__ __launch_bounds__(256) void mat_reduce(
    const float* __restrict__ part, float* __restrict__ mat)
{
    int idx = blockIdx.x * 256 + threadIdx.x;      // B_*CQ*CO = 32768
    int b   = idx / (CQ * CO);
    int rem = idx % (CQ * CO);
    float s = 0.f;
    for (int ch = 0; ch < 64; ++ch)
        s += part[((size_t)b * 64 + ch) * CQ * CO + rem];
    mat[idx] = s;
}

// ---------------------------------------------------------------------------
// Kernel 9: final  out = nan_to_num(gamma*(Vsum + Qn.matrix)*tailor) + feat
// ---------------------------------------------------------------------------
__global__ __launch_bounds__(256) void final_kernel(
    const float* __restrict__ feat, const float* __restrict__ Qt,
    const float* __restrict__ mat, const float* __restrict__ Ksum,
    const float* __restrict__ Vsum, const float* __restrict__ gamma_p,
    float* __restrict__ out)
{
    __shared__ float mat_s[CQ * CO];
    __shared__ float q_s[64 * 33];
    __shared__ float vsum_s[CO];
    __shared__ float ksum_s[CQ];
    __shared__ float tail_s[64];
    const int n0  = blockIdx.x * 64;
    const int b   = blockIdx.y;
    const int tid = threadIdx.x;
    const float gamma = gamma_p[0];

    #pragma unroll
    for (int i = 0; i < 32; ++i)
        mat_s[tid + 256 * i] = mat[(size_t)b * CQ * CO + tid + 256 * i];
    #pragma unroll
    for (int i = 0; i < 8; ++i) {
        int j = tid + 256 * i;
        int q = j & 31, p = j >> 5;
        q_s[p * 33 + q] = Qt[((size_t)b * HN + n0 + p) * CQ + q];
    }
    vsum_s[tid] = Vsum[b * CO + tid];
    if (tid < CQ) ksum_s[tid] = Ksum[b * CQ + tid];
    __syncthreads();
    if (tid < 64) {
        float e = 0.f;
        #pragma unroll
        for (int q = 0; q < CQ; ++q) e += q_s[tid * 33 + q] * ksum_s[q];
        tail_s[tid] = 1.f / fmaxf((float)HN + e, 1e-6f);
    }
    __syncthreads();

    const int p = tid & 63, cg = tid >> 6;
    float qv[CQ];
    #pragma unroll
    for (int q = 0; q < CQ; ++q) qv[q] = q_s[p * 33 + q];
    const float tl = tail_s[p];
    for (int cc = 0; cc < 64; ++cc) {
        int c = cg * 64 + cc;
        float acc = vsum_s[c];
        #pragma unroll
        for (int q = 0; q < CQ; ++q) acc += qv[q] * mat_s[q * CO + c];
        float val = gamma * acc * tl;
        if (isnan(val)) val = 0.f;
        else if (isinf(val)) val = (val > 0.f) ? 1.f : -1.f;
        size_t o = ((size_t)b * CO + c) * HN + n0 + p;
        out[o] = val + feat[o];
    }
}

// ---------------------------------------------------------------------------
extern "C" void kernel_launch(void* const* d_in, const int* in_sizes, int n_in,
                              void* d_out, int out_size, void* d_ws, size_t ws_size,
                              hipStream_t stream)
{
    const float* s5      = (const float*)d_in[0];
    const float* s4      = (const float*)d_in[1];
    const float* s3      = (const float*)d_in[2];
    const float* s2      = (const float*)d_in[3];
    const float* w_conv  = (const float*)d_in[4];
    const float* bn_g    = (const float*)d_in[5];
    const float* bn_b    = (const float*)d_in[6];
    const float* wq      = (const float*)d_in[7];
    const float* bq      = (const float*)d_in[8];
    const float* wk      = (const float*)d_in[9];
    const float* bk      = (const float*)d_in[10];
    const float* wv      = (const float*)d_in[11];
    const float* bv      = (const float*)d_in[12];
    const float* gamma_p = (const float*)d_in[13];
    float* out = (float*)d_out;
    float* ws  = (float*)d_ws;

    // ws layout (floats). V is staged in d_out (dead before final overwrite).
    float* x     = ws;                        // 16777216  (x, then feat in-place)
    float* Qt    = x     + NTOT;              // 2097152   [b][n][32]
    float* Kqn   = Qt    + (size_t)B_*HN*CQ;  // 2097152   [b][32][n]
    float* part  = Kqn   + (size_t)B_*CQ*HN;  // 2097152
    float* mat   = part  + (size_t)B_*64*CQ*CO; // 32768
    float* Ksum  = mat   + (size_t)B_*CQ*CO;  // 128
    float* Vsum  = Ksum  + B_*CQ;             // 1024
    float* scale = Vsum  + B_*CO;             // 256
    float* shift = scale + CO;                // 256
    float* V     = out;

    conv_gemm<<<dim3(HN/64, CO/64, B_), 256, 0, stream>>>(s5, s4, s3, s2, w_conv, x);
    bn_stats<<<CO, 256, 0, stream>>>(x, bn_g, bn_b, scale, shift);
    bn_relu<<<(int)(NTOT/4/256), 256, 0, stream>>>(x, scale, shift);
    qk_gemm<<<dim3(HN/64, 1, B_), 256, 0, stream>>>(x, wq, bq, wk, bk, Qt, Kqn);
    v_gemm<<<dim3(HN/64, CO/64, B_), 256, 0, stream>>>(x, wv, bv, V);
    rowsum<<<B_*CQ, 256, 0, stream>>>(Kqn, Ksum, HN);
    rowsum<<<B_*CO, 256, 0, stream>>>(V, Vsum, HN);
    kv_partial<<<dim3(64, B_), 256, 0, stream>>>(Kqn, V, part);
    mat_reduce<<<B_*CQ*CO/256, 256, 0, stream>>>(part, mat);
    final_kernel<<<dim3(HN/64, B_), 256, 0, stream>>>(x, Qt, mat, Ksum, Vsum, gamma_p, out);
}

// Round 2
// 648.805 us; speedup vs baseline: 1.7988x; 1.7988x over previous
//
#include <hip/hip_runtime.h>

#define B_   4
#define CO   256
#define CIN  1024
#define CQ   32
#define HN   16384               // H*W pixels per image
#define NTOT ((size_t)B_ * CO * HN)

typedef __attribute__((ext_vector_type(8))) short bf16x8;
typedef __attribute__((ext_vector_type(4))) float f32x4;

// fp32 -> 2x bf16 (RNE) packed into one dword
__device__ __forceinline__ unsigned bf16pair(float x, float y) {
    unsigned xu = __float_as_uint(x), yu = __float_as_uint(y);
    unsigned xr = (xu + 0x7FFFu + ((xu >> 16) & 1u)) >> 16;
    unsigned yr = (yu + 0x7FFFu + ((yu >> 16) & 1u)) >> 16;
    return xr | (yr << 16);
}

// ---------------------------------------------------------------------------
// Kernel 1: 1x1 conv as bf16-MFMA GEMM  x[b,o,n] = sum_c w[o,c] * fcat[b,c,n]
// o-tile 256 (full M, fcat read once), n-tile 64, BK 32, 16x16x32 MFMA.
// A (weight) staged [o][k] k-contig -> ds_read_b128 frags.
// B (fcat) staged [k][n] (row pad 68) -> 8x ds_read_u16 per frag (2-way, free).
// ---------------------------------------------------------------------------
__global__ __launch_bounds__(256) void conv_mfma(
    const float* __restrict__ s5, const float* __restrict__ s4,
    const float* __restrict__ s3, const float* __restrict__ s2,
    const float* __restrict__ w, float* __restrict__ x)
{
    __shared__ short As[256 * 32];      // [o][k]
    __shared__ short Bs[32 * 68];       // [k][n], padded row
    const int n0   = blockIdx.x * 64;
    const int b    = blockIdx.y;
    const int tid  = threadIdx.x;
    const int wave = tid >> 6, lane = tid & 63;
    const int l15  = lane & 15, quad = lane >> 4;

    f32x4 acc[4][4] = {};

    for (int k0 = 0; k0 < CIN; k0 += 32) {
        // --- stage A: w[0:256][k0:k0+32] ---
        #pragma unroll
        for (int i = 0; i < 4; ++i) {
            int g = tid + 256 * i;
            int o = g >> 2, kh = g & 3;                 // 8 k-elems per op
            const float* wp = w + (size_t)o * CIN + k0 + kh * 8;
            float4 u0 = *(const float4*)wp;
            float4 u1 = *(const float4*)(wp + 4);
            uint4 pk = { bf16pair(u0.x, u0.y), bf16pair(u0.z, u0.w),
                         bf16pair(u1.x, u1.y), bf16pair(u1.z, u1.w) };
            *(uint4*)&As[o * 32 + kh * 8] = pk;
        }
        // --- stage B: fcat[k0:k0+32][n0:n0+64] (tile never straddles source) ---
        const int t = k0 >> 8;
        const float* src = ((t == 0) ? s5 : (t == 1) ? s4 : (t == 2) ? s3 : s2)
                           + ((size_t)b * 256 + (k0 & 255)) * HN + n0;
        #pragma unroll
        for (int i = 0; i < 2; ++i) {
            int f = tid + 256 * i;
            int k = f >> 4, nv = f & 15;
            float4 u = *(const float4*)(src + (size_t)k * HN + nv * 4);
            uint2 pk = { bf16pair(u.x, u.y), bf16pair(u.z, u.w) };
            *(uint2*)&Bs[k * 68 + nv * 4] = pk;
        }
        __syncthreads();

        bf16x8 af[4], bfr[4];
        #pragma unroll
        for (int tm = 0; tm < 4; ++tm) {
            int o = wave * 64 + tm * 16 + l15;
            af[tm] = *(const bf16x8*)&As[o * 32 + quad * 8];
        }
        #pragma unroll
        for (int tn = 0; tn < 4; ++tn) {
            int n = tn * 16 + l15;
            bf16x8 bb;
            #pragma unroll
            for (int j = 0; j < 8; ++j)
                bb[j] = Bs[(quad * 8 + j) * 68 + n];
            bfr[tn] = bb;
        }
        #pragma unroll
        for (int tm = 0; tm < 4; ++tm)
            #pragma unroll
            for (int tn = 0; tn < 4; ++tn)
                acc[tm][tn] = __builtin_amdgcn_mfma_f32_16x16x32_bf16(
                    af[tm], bfr[tn], acc[tm][tn], 0, 0, 0);
        __syncthreads();
    }
    // epilogue: C/D layout col(n)=lane&15, row(o)=quad*4+reg
    #pragma unroll
    for (int tm = 0; tm < 4; ++tm)
        #pragma unroll
        for (int tn = 0; tn < 4; ++tn)
            #pragma unroll
            for (int r = 0; r < 4; ++r) {
                int o = wave * 64 + tm * 16 + quad * 4 + r;
                x[((size_t)b * CO + o) * HN + n0 + tn * 16 + l15] = acc[tm][tn][r];
            }
}

// ---------------------------------------------------------------------------
// Kernel 5: V projection, same MFMA structure (K=256, + bias)
// ---------------------------------------------------------------------------
__global__ __launch_bounds__(256) void v_mfma(
    const float* __restrict__ feat, const float* __restrict__ wv,
    const float* __restrict__ bv, float* __restrict__ V)
{
    __shared__ short As[256 * 32];
    __shared__ short Bs[32 * 68];
    const int n0   = blockIdx.x * 64;
    const int b    = blockIdx.y;
    const int tid  = threadIdx.x;
    const int wave = tid >> 6, lane = tid & 63;
    const int l15  = lane & 15, quad = lane >> 4;

    f32x4 acc[4][4] = {};

    for (int k0 = 0; k0 < CO; k0 += 32) {
        #pragma unroll
        for (int i = 0; i < 4; ++i) {
            int g = tid + 256 * i;
            int o = g >> 2, kh = g & 3;
            const float* wp = wv + (size_t)o * CO + k0 + kh * 8;
            float4 u0 = *(const float4*)wp;
            float4 u1 = *(const float4*)(wp + 4);
            uint4 pk = { bf16pair(u0.x, u0.y), bf16pair(u0.z, u0.w),
                         bf16pair(u1.x, u1.y), bf16pair(u1.z, u1.w) };
            *(uint4*)&As[o * 32 + kh * 8] = pk;
        }
        const float* src = feat + ((size_t)b * CO + k0) * HN + n0;
        #pragma unroll
        for (int i = 0; i < 2; ++i) {
            int f = tid + 256 * i;
            int k = f >> 4, nv = f & 15;
            float4 u = *(const float4*)(src + (size_t)k * HN + nv * 4);
            uint2 pk = { bf16pair(u.x, u.y), bf16pair(u.z, u.w) };
            *(uint2*)&Bs[k * 68 + nv * 4] = pk;
        }
        __syncthreads();

        bf16x8 af[4], bfr[4];
        #pragma unroll
        for (int tm = 0; tm < 4; ++tm) {
            int o = wave * 64 + tm * 16 + l15;
            af[tm] = *(const bf16x8*)&As[o * 32 + quad * 8];
        }
        #pragma unroll
        for (int tn = 0; tn < 4; ++tn) {
            int n = tn * 16 + l15;
            bf16x8 bb;
            #pragma unroll
            for (int j = 0; j < 8; ++j)
                bb[j] = Bs[(quad * 8 + j) * 68 + n];
            bfr[tn] = bb;
        }
        #pragma unroll
        for (int tm = 0; tm < 4; ++tm)
            #pragma unroll
            for (int tn = 0; tn < 4; ++tn)
                acc[tm][tn] = __builtin_amdgcn_mfma_f32_16x16x32_bf16(
                    af[tm], bfr[tn], acc[tm][tn], 0, 0, 0);
        __syncthreads();
    }
    #pragma unroll
    for (int tm = 0; tm < 4; ++tm)
        #pragma unroll
        for (int tn = 0; tn < 4; ++tn)
            #pragma unroll
            for (int r = 0; r < 4; ++r) {
                int o = wave * 64 + tm * 16 + quad * 4 + r;
                V[((size_t)b * CO + o) * HN + n0 + tn * 16 + l15] =
                    acc[tm][tn][r] + bv[o];
            }
}

// ---------------------------------------------------------------------------
// Kernel 2: per-channel BN stats over (B, N); writes fused scale/shift
// ---------------------------------------------------------------------------
__global__ __launch_bounds__(256) void bn_stats(
    const float* __restrict__ x, const float* __restrict__ g,
    const float* __restrict__ bt, float* __restrict__ scale,
    float* __restrict__ shift)
{
    const int o = blockIdx.x;
    const int tid = threadIdx.x;
    float s = 0.f, ss = 0.f;
    for (int b = 0; b < B_; ++b) {
        const float* p = x + ((size_t)b * CO + o) * HN;
        for (int i = tid; i < HN; i += 256) { float v = p[i]; s += v; ss += v * v; }
    }
    #pragma unroll
    for (int off = 32; off; off >>= 1) {
        s += __shfl_down(s, off, 64);
        ss += __shfl_down(ss, off, 64);
    }
    __shared__ float sh[2][4];
    if ((tid & 63) == 0) { sh[0][tid >> 6] = s; sh[1][tid >> 6] = ss; }
    __syncthreads();
    if (tid == 0) {
        float S  = sh[0][0] + sh[0][1] + sh[0][2] + sh[0][3];
        float SS = sh[1][0] + sh[1][1] + sh[1][2] + sh[1][3];
        const float cnt = (float)(B_ * HN);
        float mu  = S / cnt;
        float var = SS / cnt - mu * mu;
        float sc  = g[o] * rsqrtf(var + 1e-5f);
        scale[o] = sc;
        shift[o] = bt[o] - mu * sc;
    }
}

// ---------------------------------------------------------------------------
// Kernel 3: in-place BN affine + ReLU
// ---------------------------------------------------------------------------
__global__ __launch_bounds__(256) void bn_relu(
    float* __restrict__ x, const float* __restrict__ scale,
    const float* __restrict__ shift)
{
    size_t idx = (size_t)blockIdx.x * 256 + threadIdx.x;   // float4 index
    float4 v = ((const float4*)x)[idx];
    int o = (int)((idx * 4 / HN) % CO);
    float sc = scale[o], sf = shift[o];
    v.x = fmaxf(fmaf(v.x, sc, sf), 0.f);
    v.y = fmaxf(fmaf(v.y, sc, sf), 0.f);
    v.z = fmaxf(fmaf(v.z, sc, sf), 0.f);
    v.w = fmaxf(fmaf(v.w, sc, sf), 0.f);
    ((float4*)x)[idx] = v;
}

// ---------------------------------------------------------------------------
// Kernel 4: fused Q/K projection + per-pixel L2 norm
// ---------------------------------------------------------------------------
__global__ __launch_bounds__(256) void qk_gemm(
    const float* __restrict__ feat, const float* __restrict__ wq,
    const float* __restrict__ bq, const float* __restrict__ wk,
    const float* __restrict__ bk, float* __restrict__ Qt,
    float* __restrict__ Kqn)
{
    __shared__ float a_s[16][64];
    __shared__ float b_s[16][64];
    __shared__ float o_s[64][65];
    __shared__ float invq[64], invk[64];
    const int n0  = blockIdx.x * 64;
    const int b   = blockIdx.z;
    const int tid = threadIdx.x;
    const int tx  = tid % 16, ty = tid / 16;

    float acc[4][4] = {};
    for (int k0 = 0; k0 < CO; k0 += 16) {
        #pragma unroll
        for (int i = 0; i < 4; ++i) {
            int j = tid + 256 * i;
            int kk = j & 15, r = j >> 4;
            a_s[kk][r] = (r < 32) ? wq[(size_t)r * CO + k0 + kk]
                                  : wk[(size_t)(r - 32) * CO + k0 + kk];
        }
        const size_t cbase = ((size_t)b * CO + k0) * HN + n0;
        #pragma unroll
        for (int i = 0; i < 4; ++i) {
            int j = tid + 256 * i;
            int nn = j & 63, kk = j >> 6;
            b_s[kk][nn] = feat[cbase + (size_t)kk * HN + nn];
        }
        __syncthreads();
        #pragma unroll
        for (int kk = 0; kk < 16; ++kk) {
            float av[4], bv[4];
            #pragma unroll
            for (int i = 0; i < 4; ++i) av[i] = a_s[kk][ty * 4 + i];
            #pragma unroll
            for (int j = 0; j < 4; ++j) bv[j] = b_s[kk][tx * 4 + j];
            #pragma unroll
            for (int i = 0; i < 4; ++i)
                #pragma unroll
                for (int j = 0; j < 4; ++j) acc[i][j] += av[i] * bv[j];
        }
        __syncthreads();
    }
    #pragma unroll
    for (int i = 0; i < 4; ++i)
        #pragma unroll
        for (int j = 0; j < 4; ++j) {
            int r = ty * 4 + i;
            float bias = (r < 32) ? bq[r] : bk[r - 32];
            o_s[r][tx * 4 + j] = acc[i][j] + bias;
        }
    __syncthreads();
    if (tid < 64) {
        int p = tid;
        float sq = 0.f, sk = 0.f;
        #pragma unroll
        for (int r = 0; r < 32; ++r) { float v = o_s[r][p];      sq += v * v; }
        #pragma unroll
        for (int r = 0; r < 32; ++r) { float v = o_s[32 + r][p]; sk += v * v; }
        invq[p] = 1.f / fmaxf(sqrtf(sq), 1e-6f);
        invk[p] = 1.f / fmaxf(sqrtf(sk), 1e-6f);
    }
    __syncthreads();
    #pragma unroll
    for (int i = 0; i < 8; ++i) {
        int j = tid + 256 * i;
        int q = j & 31, p = j >> 5;
        Qt[((size_t)b * HN + n0 + p) * CQ + q] = o_s[q][p] * invq[p];
    }
    #pragma unroll
    for (int i = 0; i < 8; ++i) {
        int j = tid + 256 * i;
        int p = j & 63, q = j >> 6;
        Kqn[((size_t)b * CQ + q) * HN + n0 + p] = o_s[32 + q][p] * invk[p];
    }
}

// ---------------------------------------------------------------------------
// Kernel 6: contiguous row-sum
// ---------------------------------------------------------------------------
__global__ __launch_bounds__(256) void rowsum(
    const float* __restrict__ src, float* __restrict__ dst, int rowlen)
{
    const size_t r = blockIdx.x;
    const int tid = threadIdx.x;
    float s = 0.f;
    const float* p = src + r * (size_t)rowlen;
    for (int i = tid; i < rowlen; i += 256) s += p[i];
    #pragma unroll
    for (int off = 32; off; off >>= 1) s += __shfl_down(s, off, 64);
    __shared__ float sh[4];
    if ((tid & 63) == 0) sh[tid >> 6] = s;
    __syncthreads();
    if (tid == 0) dst[r] = sh[0] + sh[1] + sh[2] + sh[3];
}

// ---------------------------------------------------------------------------
// Kernel 7: KV outer-product partials
// ---------------------------------------------------------------------------
__global__ __launch_bounds__(256) void kv_partial(
    const float* __restrict__ Kqn, const float* __restrict__ V,
    float* __restrict__ part)
{
    __shared__ float a_s[CQ][33];
    __shared__ float v_s[32][CO + 1];
    const int chunk = blockIdx.x;
    const int b     = blockIdx.y;
    const int tid   = threadIdx.x;
    const int tc = tid & 31, tq = tid >> 5;
    float acc[4][8] = {};
    const int p0 = chunk * 256;

    for (int nt = 0; nt < 8; ++nt) {
        const int pb = p0 + nt * 32;
        #pragma unroll
        for (int i = 0; i < 4; ++i) {
            int j = tid + 256 * i;
            int nn = j & 31, q = j >> 5;
            a_s[q][nn] = Kqn[((size_t)b * CQ + q) * HN + pb + nn];
        }
        #pragma unroll
        for (int i = 0; i < 32; ++i) {
            int j = tid + 256 * i;
            int nn = j & 31, c = j >> 5;
            v_s[nn][c] = V[((size_t)b * CO + c) * HN + pb + nn];
        }
        __syncthreads();
        #pragma unroll 4
        for (int nn = 0; nn < 32; ++nn) {
            float av[4], vv[8];
            #pragma unroll
            for (int qi = 0; qi < 4; ++qi) av[qi] = a_s[tq * 4 + qi][nn];
            #pragma unroll
            for (int ci = 0; ci < 8; ++ci) vv[ci] = v_s[nn][tc + 32 * ci];
            #pragma unroll
            for (int qi = 0; qi < 4; ++qi)
                #pragma unroll
                for (int ci = 0; ci < 8; ++ci) acc[qi][ci] += av[qi] * vv[ci];
        }
        __syncthreads();
    }
    float* dst = part + ((size_t)b * 64 + chunk) * CQ * CO;
    #pragma unroll
    for (int qi = 0; qi < 4; ++qi)
        #pragma unroll
        for (int ci = 0; ci < 8; ++ci)
            dst[(tq * 4 + qi) * CO + tc + 32 * ci] = acc[qi][ci];
}

// ---------------------------------------------------------------------------
// Kernel 8: reduce partials -> matrix[b,q,c]
// ---------------------------------------------------------------------------
__global__ __launch_bounds__(256) void mat_reduce(
    const float* __restrict__ part, float* __restrict__ mat)
{
    int idx = blockIdx.x * 256 + threadIdx.x;
    int b   = idx / (CQ * CO);
    int rem = idx % (CQ * CO);
    float s = 0.f;
    for (int ch = 0; ch < 64; ++ch)
        s += part[((size_t)b * 64 + ch) * CQ * CO + rem];
    mat[idx] = s;
}

// ---------------------------------------------------------------------------
// Kernel 9: final  out = nan_to_num(gamma*(Vsum + Qn.matrix)*tailor) + feat
// ---------------------------------------------------------------------------
__global__ __launch_bounds__(256) void final_kernel(
    const float* __restrict__ feat, const float* __restrict__ Qt,
    const float* __restrict__ mat, const float* __restrict__ Ksum,
    const float* __restrict__ Vsum, const float* __restrict__ gamma_p,
    float* __restrict__ out)
{
    __shared__ float mat_s[CQ * CO];
    __shared__ float q_s[64 * 33];
    __shared__ float vsum_s[CO];
    __shared__ float ksum_s[CQ];
    __shared__ float tail_s[64];
    const int n0  = blockIdx.x * 64;
    const int b   = blockIdx.y;
    const int tid = threadIdx.x;
    const float gamma = gamma_p[0];

    #pragma unroll
    for (int i = 0; i < 32; ++i)
        mat_s[tid + 256 * i] = mat[(size_t)b * CQ * CO + tid + 256 * i];
    #pragma unroll
    for (int i = 0; i < 8; ++i) {
        int j = tid + 256 * i;
        int q = j & 31, p = j >> 5;
        q_s[p * 33 + q] = Qt[((size_t)b * HN + n0 + p) * CQ + q];
    }
    vsum_s[tid] = Vsum[b * CO + tid];
    if (tid < CQ) ksum_s[tid] = Ksum[b * CQ + tid];
    __syncthreads();
    if (tid < 64) {
        float e = 0.f;
        #pragma unroll
        for (int q = 0; q < CQ; ++q) e += q_s[tid * 33 + q] * ksum_s[q];
        tail_s[tid] = 1.f / fmaxf((float)HN + e, 1e-6f);
    }
    __syncthreads();

    const int p = tid & 63, cg = tid >> 6;
    float qv[CQ];
    #pragma unroll
    for (int q = 0; q < CQ; ++q) qv[q] = q_s[p * 33 + q];
    const float tl = tail_s[p];
    for (int cc = 0; cc < 64; ++cc) {
        int c = cg * 64 + cc;
        float acc = vsum_s[c];
        #pragma unroll
        for (int q = 0; q < CQ; ++q) acc += qv[q] * mat_s[q * CO + c];
        float val = gamma * acc * tl;
        if (isnan(val)) val = 0.f;
        else if (isinf(val)) val = (val > 0.f) ? 1.f : -1.f;
        size_t o = ((size_t)b * CO + c) * HN + n0 + p;
        out[o] = val + feat[o];
    }
}

// ---------------------------------------------------------------------------
extern "C" void kernel_launch(void* const* d_in, const int* in_sizes, int n_in,
                              void* d_out, int out_size, void* d_ws, size_t ws_size,
                              hipStream_t stream)
{
    const float* s5      = (const float*)d_in[0];
    const float* s4      = (const float*)d_in[1];
    const float* s3      = (const float*)d_in[2];
    const float* s2      = (const float*)d_in[3];
    const float* w_conv  = (const float*)d_in[4];
    const float* bn_g    = (const float*)d_in[5];
    const float* bn_b    = (const float*)d_in[6];
    const float* wq      = (const float*)d_in[7];
    const float* bq      = (const float*)d_in[8];
    const float* wk      = (const float*)d_in[9];
    const float* bk      = (const float*)d_in[10];
    const float* wv      = (const float*)d_in[11];
    const float* bv      = (const float*)d_in[12];
    const float* gamma_p = (const float*)d_in[13];
    float* out = (float*)d_out;
    float* ws  = (float*)d_ws;

    float* x     = ws;                          // 16.7M floats (x, then feat)
    float* Qt    = x     + NTOT;                // [b][n][32]
    float* Kqn   = Qt    + (size_t)B_*HN*CQ;    // [b][32][n]
    float* part  = Kqn   + (size_t)B_*CQ*HN;
    float* mat   = part  + (size_t)B_*64*CQ*CO;
    float* Ksum  = mat   + (size_t)B_*CQ*CO;
    float* Vsum  = Ksum  + B_*CQ;
    float* scale = Vsum  + B_*CO;
    float* shift = scale + CO;
    float* V     = out;                         // staged in d_out (dead by final)

    conv_mfma<<<dim3(HN/64, B_), 256, 0, stream>>>(s5, s4, s3, s2, w_conv, x);
    bn_stats<<<CO, 256, 0, stream>>>(x, bn_g, bn_b, scale, shift);
    bn_relu<<<(int)(NTOT/4/256), 256, 0, stream>>>(x, scale, shift);
    qk_gemm<<<dim3(HN/64, 1, B_), 256, 0, stream>>>(x, wq, bq, wk, bk, Qt, Kqn);
    v_mfma<<<dim3(HN/64, B_), 256, 0, stream>>>(x, wv, bv, V);
    rowsum<<<B_*CQ, 256, 0, stream>>>(Kqn, Ksum, HN);
    rowsum<<<B_*CO, 256, 0, stream>>>(V, Vsum, HN);
    kv_partial<<<dim3(64, B_), 256, 0, stream>>>(Kqn, V, part);
    mat_reduce<<<B_*CQ*CO/256, 256, 0, stream>>>(part, mat);
    final_kernel<<<dim3(HN/64, B_), 256, 0, stream>>>(x, Qt, mat, Ksum, Vsum, gamma_p, out);
}

// Round 3
// 518.062 us; speedup vs baseline: 2.2528x; 1.2524x over previous
//
#include <hip/hip_runtime.h>

#define B_   4
#define CO   256
#define CIN  1024
#define CQ   32
#define HN   16384
#define NPIX 65536                       // B_*HN flat pixels
#define NTOT ((size_t)B_ * CO * HN)

typedef unsigned short ushort_t;
typedef __attribute__((ext_vector_type(8))) short bf16x8;
typedef __attribute__((ext_vector_type(4))) float f32x4;

__device__ __forceinline__ unsigned bf16pair(float x, float y) {
    unsigned xu = __float_as_uint(x), yu = __float_as_uint(y);
    unsigned xr = (xu + 0x7FFFu + ((xu >> 16) & 1u)) >> 16;
    unsigned yr = (yu + 0x7FFFu + ((yu >> 16) & 1u)) >> 16;
    return xr | (yr << 16);
}
__device__ __forceinline__ ushort_t bf16of(float x) {
    unsigned u = __float_as_uint(x);
    return (ushort_t)((u + 0x7FFFu + ((u >> 16) & 1u)) >> 16);
}
__device__ __forceinline__ float bf2f(ushort_t h) {
    return __uint_as_float(((unsigned)h) << 16);
}
__device__ __forceinline__ void unpack8(uint4 u, float* f) {
    f[0] = __uint_as_float(u.x << 16); f[1] = __uint_as_float(u.x & 0xffff0000u);
    f[2] = __uint_as_float(u.y << 16); f[3] = __uint_as_float(u.y & 0xffff0000u);
    f[4] = __uint_as_float(u.z << 16); f[5] = __uint_as_float(u.z & 0xffff0000u);
    f[6] = __uint_as_float(u.w << 16); f[7] = __uint_as_float(u.w & 0xffff0000u);
}
// async global->LDS, 16B per lane. lds must be wave-uniform; lane i lands at lds + i*16.
__device__ __forceinline__ void async16(void* lds, const void* g) {
    __builtin_amdgcn_global_load_lds(
        (const __attribute__((address_space(1))) void*)g,
        (__attribute__((address_space(3))) void*)lds, 16, 0, 0);
}

// ---------------------------------------------------------------------------
// weights fp32 -> bf16 (w_conv, wq|wk fused rows 0-31/32-63, wv)
// ---------------------------------------------------------------------------
__global__ __launch_bounds__(256) void wcvt(
    const float* __restrict__ w, const float* __restrict__ wq,
    const float* __restrict__ wk, const float* __restrict__ wv,
    ushort_t* __restrict__ w_bf, ushort_t* __restrict__ wqk_bf,
    ushort_t* __restrict__ wv_bf)
{
    int i = blockIdx.x * 256 + threadIdx.x;          // 0..344063
    if (i < 262144) {
        w_bf[i] = bf16of(w[i]);
    } else if (i < 278528) {
        int l = i - 262144; int row = l >> 8, col = l & 255;
        float v = (row < 32) ? wq[row * 256 + col] : wk[(row - 32) * 256 + col];
        wqk_bf[l] = bf16of(v);
    } else {
        int l = i - 278528;
        wv_bf[l] = bf16of(wv[l]);
    }
}

// ---------------------------------------------------------------------------
// conv: x[b,o,n] = sum_c w[o,c]*fcat[b,c,n], bf16 MFMA, out bf16.
// o-tile 128 x n-tile 128, BK 32. A (weights bf16) via global_load_lds.
// B (fcat fp32) VALU-converted into LDS [k][130] (2-way-free scalar frag reads).
// ---------------------------------------------------------------------------
__global__ __launch_bounds__(256) void conv_mfma2(
    const float* __restrict__ s5, const float* __restrict__ s4,
    const float* __restrict__ s3, const float* __restrict__ s2,
    const ushort_t* __restrict__ w_bf, ushort_t* __restrict__ xb)
{
    __shared__ ushort_t Aw[128 * 32];     // [o][k], unpadded (DMA layout)
    __shared__ ushort_t Bf[32 * 130];     // [k][n], pad 130
    const int o0 = blockIdx.x * 128;
    const int n0 = blockIdx.y * 128;
    const int b  = blockIdx.z;
    const int tid = threadIdx.x;
    const int wave = tid >> 6, lane = tid & 63, l15 = lane & 15, quad = lane >> 4;
    const int wm = wave & 1, wn = wave >> 1;
    f32x4 acc[4][4] = {};

    for (int k0 = 0; k0 < CIN; k0 += 32) {
        #pragma unroll
        for (int r = 0; r < 2; ++r) {
            int row = r * 64 + wave * 16;
            const ushort_t* g = w_bf + (size_t)(o0 + row + (lane >> 2)) * CIN
                                + k0 + (lane & 3) * 8;
            async16(&Aw[row * 32], g);
        }
        const int t = k0 >> 8;
        const float* src = ((t == 0) ? s5 : (t == 1) ? s4 : (t == 2) ? s3 : s2)
                           + ((size_t)b * 256 + (k0 & 255)) * HN + n0;
        #pragma unroll
        for (int i = 0; i < 4; ++i) {
            int gi = tid + 256 * i;
            int k = gi >> 5, n4 = gi & 31;
            float4 u = *(const float4*)(src + (size_t)k * HN + n4 * 4);
            *(unsigned*)&Bf[k * 130 + n4 * 4]     = bf16pair(u.x, u.y);
            *(unsigned*)&Bf[k * 130 + n4 * 4 + 2] = bf16pair(u.z, u.w);
        }
        __syncthreads();
        bf16x8 af[4], bfv[4];
        #pragma unroll
        for (int tm = 0; tm < 4; ++tm)
            af[tm] = *(const bf16x8*)&Aw[(wm * 64 + tm * 16 + l15) * 32 + quad * 8];
        #pragma unroll
        for (int tn = 0; tn < 4; ++tn) {
            int nl = wn * 64 + tn * 16 + l15;
            bf16x8 bb;
            #pragma unroll
            for (int j = 0; j < 8; ++j) bb[j] = (short)Bf[(quad * 8 + j) * 130 + nl];
            bfv[tn] = bb;
        }
        #pragma unroll
        for (int tm = 0; tm < 4; ++tm)
            #pragma unroll
            for (int tn = 0; tn < 4; ++tn)
                acc[tm][tn] = __builtin_amdgcn_mfma_f32_16x16x32_bf16(
                    af[tm], bfv[tn], acc[tm][tn], 0, 0, 0);
        __syncthreads();
    }
    #pragma unroll
    for (int tm = 0; tm < 4; ++tm)
        #pragma unroll
        for (int r = 0; r < 4; ++r) {
            int o = o0 + wm * 64 + tm * 16 + quad * 4 + r;
            size_t base = ((size_t)b * CO + o) * HN + n0;
            #pragma unroll
            for (int tn = 0; tn < 4; ++tn)
                xb[base + wn * 64 + tn * 16 + l15] = bf16of(acc[tm][tn][r]);
        }
}

// ---------------------------------------------------------------------------
// BN stats: atomic per-channel sum/sumsq from bf16 x
// ---------------------------------------------------------------------------
__global__ __launch_bounds__(256) void bn_stats(
    const ushort_t* __restrict__ xb, float* __restrict__ accum)
{
    const int o = blockIdx.x, seg = blockIdx.y, tid = threadIdx.x;
    const int wave = tid >> 6, lane = tid & 63;
    float s = 0.f, ss = 0.f;
    for (int b = 0; b < B_; ++b) {
        const ushort_t* p = xb + ((size_t)(b * CO + o)) * HN + seg * 2048 + tid * 8;
        uint4 u = *(const uint4*)p;
        float f[8]; unpack8(u, f);
        #pragma unroll
        for (int j = 0; j < 8; ++j) { s += f[j]; ss += f[j] * f[j]; }
    }
    #pragma unroll
    for (int m = 1; m < 64; m <<= 1) { s += __shfl_xor(s, m); ss += __shfl_xor(ss, m); }
    __shared__ float shs[4], shss[4];
    if (lane == 0) { shs[wave] = s; shss[wave] = ss; }
    __syncthreads();
    if (tid == 0) {
        atomicAdd(&accum[o],       shs[0] + shs[1] + shs[2] + shs[3]);
        atomicAdd(&accum[256 + o], shss[0] + shss[1] + shss[2] + shss[3]);
    }
}

__global__ __launch_bounds__(256) void bn_finalize(
    const float* __restrict__ accum, const float* __restrict__ g,
    const float* __restrict__ bt, float* __restrict__ scale,
    float* __restrict__ shift)
{
    int o = threadIdx.x;
    float mu  = accum[o] / (float)NPIX;
    float var = accum[256 + o] / (float)NPIX - mu * mu;
    float sc  = g[o] * rsqrtf(var + 1e-5f);
    scale[o] = sc;
    shift[o] = bt[o] - mu * sc;
}

// ---------------------------------------------------------------------------
// BN+ReLU + transpose: xb [b][c][n] bf16 -> featT [flat n][c] bf16 (64x64 tiles)
// ---------------------------------------------------------------------------
__global__ __launch_bounds__(256) void bnrelu_t(
    const ushort_t* __restrict__ xb, const float* __restrict__ scale,
    const float* __restrict__ shift, ushort_t* __restrict__ featT)
{
    __shared__ ushort_t sh[64 * 68];
    const int hn0 = blockIdx.x * 64, c0 = blockIdx.y * 64, b = blockIdx.z;
    const int tid = threadIdx.x;
    {
        int cl = tid >> 2, seg = tid & 3;
        float sc = scale[c0 + cl], sf = shift[c0 + cl];
        const ushort_t* src = xb + ((size_t)(b * CO + c0 + cl)) * HN + hn0 + seg * 16;
        #pragma unroll
        for (int h = 0; h < 2; ++h) {
            uint4 u = *(const uint4*)(src + h * 8);
            float f[8]; unpack8(u, f);
            #pragma unroll
            for (int j = 0; j < 8; ++j) {
                float v = fmaxf(fmaf(sc, f[j], sf), 0.f);
                sh[(seg * 16 + h * 8 + j) * 68 + cl] = bf16of(v);
            }
        }
    }
    __syncthreads();
    {
        int nl = tid >> 2, seg = tid & 3;
        size_t gn = (size_t)b * HN + hn0 + nl;
        ushort_t* dst = featT + gn * CO + c0 + seg * 16;
        #pragma unroll
        for (int j = 0; j < 4; ++j)
            *(uint2*)(dst + j * 4) = *(const uint2*)&sh[nl * 68 + seg * 16 + j * 4];
    }
}

// ---------------------------------------------------------------------------
// QK projection: D[n][64ch] = featT x wqk^T, + bias, per-pixel L2 norm,
// writes Qt/Kt [n][32] bf16, Ksum atomics. Clean DMA GEMM, K=256.
// ---------------------------------------------------------------------------
__global__ __launch_bounds__(256) void qk_mfma(
    const ushort_t* __restrict__ featT, const ushort_t* __restrict__ wqk_bf,
    const float* __restrict__ bq, const float* __restrict__ bk,
    ushort_t* __restrict__ Qt, ushort_t* __restrict__ Kt,
    float* __restrict__ Ksum)
{
    __shared__ ushort_t At[128 * 32];
    __shared__ ushort_t Bt[64 * 32];
    const int n0 = blockIdx.x * 128;       // flat pixel
    const int b  = n0 >> 14;
    const int tid = threadIdx.x;
    const int wave = tid >> 6, lane = tid & 63, l15 = lane & 15, quad = lane >> 4;
    const int nsub = (wave & 1) * 64;
    const int isK  = wave >> 1;
    f32x4 acc[4][2] = {};

    for (int k0 = 0; k0 < CO; k0 += 32) {
        #pragma unroll
        for (int r = 0; r < 2; ++r) {
            int row = r * 64 + wave * 16;
            const ushort_t* g = featT + (size_t)(n0 + row + (lane >> 2)) * CO
                                + k0 + (lane & 3) * 8;
            async16(&At[row * 32], g);
        }
        {
            int row = wave * 16;
            const ushort_t* g = wqk_bf + (size_t)(row + (lane >> 2)) * CO
                                + k0 + (lane & 3) * 8;
            async16(&Bt[row * 32], g);
        }
        __syncthreads();
        bf16x8 af[4], bfv[2];
        #pragma unroll
        for (int tm = 0; tm < 4; ++tm)
            af[tm] = *(const bf16x8*)&At[(nsub + tm * 16 + l15) * 32 + quad * 8];
        #pragma unroll
        for (int tc = 0; tc < 2; ++tc)
            bfv[tc] = *(const bf16x8*)&Bt[(isK * 32 + tc * 16 + l15) * 32 + quad * 8];
        #pragma unroll
        for (int tm = 0; tm < 4; ++tm)
            #pragma unroll
            for (int tc = 0; tc < 2; ++tc)
                acc[tm][tc] = __builtin_amdgcn_mfma_f32_16x16x32_bf16(
                    af[tm], bfv[tc], acc[tm][tc], 0, 0, 0);
        __syncthreads();
    }
    const float bias0 = isK ? bk[l15]      : bq[l15];
    const float bias1 = isK ? bk[16 + l15] : bq[16 + l15];
    ushort_t* dst = isK ? Kt : Qt;
    float ks0 = 0.f, ks1 = 0.f;
    #pragma unroll
    for (int tm = 0; tm < 4; ++tm)
        #pragma unroll
        for (int r = 0; r < 4; ++r) {
            float v0 = acc[tm][0][r] + bias0;
            float v1 = acc[tm][1][r] + bias1;
            float sq = v0 * v0 + v1 * v1;
            sq += __shfl_xor(sq, 1); sq += __shfl_xor(sq, 2);
            sq += __shfl_xor(sq, 4); sq += __shfl_xor(sq, 8);
            float inv = 1.f / fmaxf(sqrtf(sq), 1e-6f);
            v0 *= inv; v1 *= inv;
            int n = n0 + nsub + tm * 16 + quad * 4 + r;
            dst[(size_t)n * CQ + l15]      = bf16of(v0);
            dst[(size_t)n * CQ + 16 + l15] = bf16of(v1);
            ks0 += v0; ks1 += v1;
        }
    if (isK) {
        ks0 += __shfl_xor(ks0, 16); ks0 += __shfl_xor(ks0, 32);
        ks1 += __shfl_xor(ks1, 16); ks1 += __shfl_xor(ks1, 32);
        if (quad == 0) {
            atomicAdd(&Ksum[b * CQ + l15],      ks0);
            atomicAdd(&Ksum[b * CQ + 16 + l15], ks1);
        }
    }
}

// ---------------------------------------------------------------------------
// V projection: Vt [flat n][256] bf16 (into d_out) + bias + Vsum atomics.
// ---------------------------------------------------------------------------
__global__ __launch_bounds__(256) void v_mfma2(
    const ushort_t* __restrict__ featT, const ushort_t* __restrict__ wv_bf,
    const float* __restrict__ bv, ushort_t* __restrict__ Vt,
    float* __restrict__ Vsum)
{
    __shared__ ushort_t At[128 * 32];
    __shared__ ushort_t Bt[128 * 32];
    const int n0  = blockIdx.x * 128;
    const int co0 = blockIdx.y * 128;
    const int b   = n0 >> 14;
    const int tid = threadIdx.x;
    const int wave = tid >> 6, lane = tid & 63, l15 = lane & 15, quad = lane >> 4;
    const int wm = wave & 1, wn = wave >> 1;
    f32x4 acc[4][4] = {};

    for (int k0 = 0; k0 < CO; k0 += 32) {
        #pragma unroll
        for (int r = 0; r < 2; ++r) {
            int row = r * 64 + wave * 16;
            const ushort_t* ga = featT + (size_t)(n0 + row + (lane >> 2)) * CO
                                 + k0 + (lane & 3) * 8;
            async16(&At[row * 32], ga);
            const ushort_t* gb = wv_bf + (size_t)(co0 + row + (lane >> 2)) * CO
                                 + k0 + (lane & 3) * 8;
            async16(&Bt[row * 32], gb);
        }
        __syncthreads();
        bf16x8 af[4], bfv[4];
        #pragma unroll
        for (int tm = 0; tm < 4; ++tm)
            af[tm] = *(const bf16x8*)&At[(wm * 64 + tm * 16 + l15) * 32 + quad * 8];
        #pragma unroll
        for (int tn = 0; tn < 4; ++tn)
            bfv[tn] = *(const bf16x8*)&Bt[(wn * 64 + tn * 16 + l15) * 32 + quad * 8];
        #pragma unroll
        for (int tm = 0; tm < 4; ++tm)
            #pragma unroll
            for (int tn = 0; tn < 4; ++tn)
                acc[tm][tn] = __builtin_amdgcn_mfma_f32_16x16x32_bf16(
                    af[tm], bfv[tn], acc[tm][tn], 0, 0, 0);
        __syncthreads();
    }
    float bvl[4], vsum_p[4] = {};
    #pragma unroll
    for (int tn = 0; tn < 4; ++tn) bvl[tn] = bv[co0 + wn * 64 + tn * 16 + l15];
    #pragma unroll
    for (int tm = 0; tm < 4; ++tm)
        #pragma unroll
        for (int r = 0; r < 4; ++r) {
            int n = n0 + wm * 64 + tm * 16 + quad * 4 + r;
            size_t rb = (size_t)n * CO;
            #pragma unroll
            for (int tn = 0; tn < 4; ++tn) {
                float val = acc[tm][tn][r] + bvl[tn];
                Vt[rb + co0 + wn * 64 + tn * 16 + l15] = bf16of(val);
                vsum_p[tn] += val;
            }
        }
    #pragma unroll
    for (int tn = 0; tn < 4; ++tn) {
        float s = vsum_p[tn];
        s += __shfl_xor(s, 16); s += __shfl_xor(s, 32);
        if (quad == 0)
            atomicAdd(&Vsum[b * CO + co0 + wn * 64 + tn * 16 + l15], s);
    }
}

// ---------------------------------------------------------------------------
// KV: matT[b][c][q] += sum_n Kt[n][q] * Vt[n][c]  (fp32 accum, atomics)
// ---------------------------------------------------------------------------
__global__ __launch_bounds__(256) void kv_outer(
    const ushort_t* __restrict__ Kt, const ushort_t* __restrict__ Vt,
    float* __restrict__ matT)
{
    __shared__ float k_s[32 * 36];
    __shared__ float v_s[32 * 268];
    const int chunk = blockIdx.x;          // 0..255, 256 pixels each
    const int b  = chunk >> 6;
    const int nb = chunk * 256;
    const int tid = threadIdx.x;
    const int tq = tid >> 5, tc = tid & 31;
    float acc[4][8] = {};

    for (int slab = 0; slab < 8; ++slab) {
        int ns = nb + slab * 32;
        {   // stage Kt [32n][32q]
            int nn = tid >> 3, qs = tid & 7;
            uint2 u = *(const uint2*)&Kt[(size_t)(ns + nn) * CQ + qs * 4];
            k_s[nn * 36 + qs * 4 + 0] = __uint_as_float(u.x << 16);
            k_s[nn * 36 + qs * 4 + 1] = __uint_as_float(u.x & 0xffff0000u);
            k_s[nn * 36 + qs * 4 + 2] = __uint_as_float(u.y << 16);
            k_s[nn * 36 + qs * 4 + 3] = __uint_as_float(u.y & 0xffff0000u);
        }
        #pragma unroll
        for (int p = 0; p < 4; ++p) {      // stage Vt [32n][256c]
            int nn = p * 8 + (tid & 7), cs = tid >> 3;
            uint4 u = *(const uint4*)&Vt[(size_t)(ns + nn) * CO + cs * 8];
            float f[8]; unpack8(u, f);
            *(float4*)&v_s[nn * 268 + cs * 8]     = make_float4(f[0], f[1], f[2], f[3]);
            *(float4*)&v_s[nn * 268 + cs * 8 + 4] = make_float4(f[4], f[5], f[6], f[7]);
        }
        __syncthreads();
        #pragma unroll 4
        for (int nn = 0; nn < 32; ++nn) {
            float4 kq = *(const float4*)&k_s[nn * 36 + tq * 4];
            float vv[8];
            #pragma unroll
            for (int ci = 0; ci < 8; ++ci) vv[ci] = v_s[nn * 268 + tc + 32 * ci];
            #pragma unroll
            for (int ci = 0; ci < 8; ++ci) {
                acc[0][ci] += kq.x * vv[ci];
                acc[1][ci] += kq.y * vv[ci];
                acc[2][ci] += kq.z * vv[ci];
                acc[3][ci] += kq.w * vv[ci];
            }
        }
        __syncthreads();
    }
    #pragma unroll
    for (int qi = 0; qi < 4; ++qi)
        #pragma unroll
        for (int ci = 0; ci < 8; ++ci)
            atomicAdd(&matT[b * 8192 + (tc + 32 * ci) * CQ + tq * 4 + qi],
                      acc[qi][ci]);
}

// ---------------------------------------------------------------------------
// tailor[n] = 1 / max(HN + Qn[n].Ksum[b], 1e-6)
// ---------------------------------------------------------------------------
__global__ __launch_bounds__(256) void tailor_k(
    const ushort_t* __restrict__ Qt, const float* __restrict__ Ksum,
    float* __restrict__ tailor)
{
    __shared__ float ks[CQ];
    const int n = blockIdx.x * 256 + threadIdx.x;
    const int b = n >> 14;
    if (threadIdx.x < CQ) ks[threadIdx.x] = Ksum[b * CQ + threadIdx.x];
    __syncthreads();
    const uint4* q = (const uint4*)&Qt[(size_t)n * CQ];
    float e = 0.f;
    #pragma unroll
    for (int i = 0; i < 4; ++i) {
        float f[8]; unpack8(q[i], f);
        #pragma unroll
        for (int j = 0; j < 8; ++j) e += f[j] * ks[i * 8 + j];
    }
    tailor[n] = 1.f / fmaxf((float)HN + e, 1e-6f);
}

// ---------------------------------------------------------------------------
// final: out[b,c,hn] = nan2num(gamma*(Vsum[c] + sum_q matT[c][q]Qt[n][q])*tailor[n])
//        + relu(scale[c]*x[b,c,hn]+shift[c]).  Single-K-step MFMA, no LDS.
// ---------------------------------------------------------------------------
__global__ __launch_bounds__(256) void final_mfma(
    const ushort_t* __restrict__ xb, const ushort_t* __restrict__ Qt,
    const float* __restrict__ matT, const float* __restrict__ Vsum,
    const float* __restrict__ tailor, const float* __restrict__ scale,
    const float* __restrict__ shift, const float* __restrict__ gamma_p,
    float* __restrict__ out)
{
    const int c0 = blockIdx.x * 128;
    const int n0 = blockIdx.y * 128;       // flat pixel
    const int b  = n0 >> 14, hn0 = n0 & 16383;
    const int tid = threadIdx.x;
    const int wave = tid >> 6, lane = tid & 63, l15 = lane & 15, quad = lane >> 4;
    const int wm = wave & 1, wn = wave >> 1;
    const float gamma = gamma_p[0];

    bf16x8 af[4], bfv[4];
    #pragma unroll
    for (int tm = 0; tm < 4; ++tm) {
        int c = c0 + wm * 64 + tm * 16 + l15;
        const float* mp = matT + b * 8192 + c * CQ + quad * 8;
        float4 m0 = *(const float4*)mp;
        float4 m1 = *(const float4*)(mp + 4);
        union { bf16x8 v; unsigned u[4]; } t;
        t.u[0] = bf16pair(m0.x, m0.y); t.u[1] = bf16pair(m0.z, m0.w);
        t.u[2] = bf16pair(m1.x, m1.y); t.u[3] = bf16pair(m1.z, m1.w);
        af[tm] = t.v;
    }
    #pragma unroll
    for (int tn = 0; tn < 4; ++tn) {
        int n = n0 + wn * 64 + tn * 16 + l15;
        bfv[tn] = *(const bf16x8*)&Qt[(size_t)n * CQ + quad * 8];
    }
    f32x4 acc[4][4] = {};
    #pragma unroll
    for (int tm = 0; tm < 4; ++tm)
        #pragma unroll
        for (int tn = 0; tn < 4; ++tn)
            acc[tm][tn] = __builtin_amdgcn_mfma_f32_16x16x32_bf16(
                af[tm], bfv[tn], acc[tm][tn], 0, 0, 0);

    float tl[4];
    #pragma unroll
    for (int tn = 0; tn < 4; ++tn) tl[tn] = tailor[n0 + wn * 64 + tn * 16 + l15];

    #pragma unroll
    for (int tm = 0; tm < 4; ++tm)
        #pragma unroll
        for (int r = 0; r < 4; ++r) {
            int c = c0 + wm * 64 + tm * 16 + quad * 4 + r;
            float vs = Vsum[b * CO + c];
            float sc = scale[c], sf = shift[c];
            size_t rowbase = ((size_t)(b * CO + c)) * HN + hn0;
            #pragma unroll
            for (int tn = 0; tn < 4; ++tn) {
                int nl = wn * 64 + tn * 16 + l15;
                float val = gamma * (acc[tm][tn][r] + vs) * tl[tn];
                if (isnan(val)) val = 0.f;
                else if (isinf(val)) val = (val > 0.f) ? 1.f : -1.f;
                float feat = fmaxf(fmaf(sc, bf2f(xb[rowbase + nl]), sf), 0.f);
                out[rowbase + nl] = val + feat;
            }
        }
}

// ---------------------------------------------------------------------------
extern "C" void kernel_launch(void* const* d_in, const int* in_sizes, int n_in,
                              void* d_out, int out_size, void* d_ws, size_t ws_size,
                              hipStream_t stream)
{
    const float* s5      = (const float*)d_in[0];
    const float* s4      = (const float*)d_in[1];
    const float* s3      = (const float*)d_in[2];
    const float* s2      = (const float*)d_in[3];
    const float* w_conv  = (const float*)d_in[4];
    const float* bn_g    = (const float*)d_in[5];
    const float* bn_b    = (const float*)d_in[6];
    const float* wq      = (const float*)d_in[7];
    const float* bq      = (const float*)d_in[8];
    const float* wk      = (const float*)d_in[9];
    const float* bk      = (const float*)d_in[10];
    const float* wv      = (const float*)d_in[11];
    const float* bv      = (const float*)d_in[12];
    const float* gamma_p = (const float*)d_in[13];

    char* p = (char*)d_ws;
    ushort_t* xb     = (ushort_t*)p;  p += NTOT * 2;                 // 32 MB
    ushort_t* featT  = (ushort_t*)p;  p += NTOT * 2;                 // 32 MB
    ushort_t* Qt     = (ushort_t*)p;  p += (size_t)NPIX * CQ * 2;    // 4 MB
    ushort_t* Kt     = (ushort_t*)p;  p += (size_t)NPIX * CQ * 2;    // 4 MB
    ushort_t* w_bf   = (ushort_t*)p;  p += (size_t)CO * CIN * 2;     // 512 KB
    ushort_t* wqk_bf = (ushort_t*)p;  p += 64 * CO * 2;              // 32 KB
    ushort_t* wv_bf  = (ushort_t*)p;  p += (size_t)CO * CO * 2;      // 128 KB
    float* matT  = (float*)p;                                        // 32768 f
    float* Ksum  = matT + (size_t)B_ * CO * CQ;                      // 128 f
    float* Vsum  = Ksum + B_ * CQ;                                   // 1024 f
    float* accum = Vsum + B_ * CO;                                   // 512 f
    size_t zero_bytes = (size_t)(32768 + 128 + 1024 + 512) * 4;
    p += zero_bytes;
    float* scale  = (float*)p;  p += 256 * 4;
    float* shift  = (float*)p;  p += 256 * 4;
    float* tailor = (float*)p;  p += (size_t)NPIX * 4;

    hipMemsetAsync(matT, 0, zero_bytes, stream);
    wcvt<<<1344, 256, 0, stream>>>(w_conv, wq, wk, wv, w_bf, wqk_bf, wv_bf);
    conv_mfma2<<<dim3(2, 128, B_), 256, 0, stream>>>(s5, s4, s3, s2, w_bf, xb);
    bn_stats<<<dim3(256, 8), 256, 0, stream>>>(xb, accum);
    bn_finalize<<<1, 256, 0, stream>>>(accum, bn_g, bn_b, scale, shift);
    bnrelu_t<<<dim3(256, 4, B_), 256, 0, stream>>>(xb, scale, shift, featT);
    qk_mfma<<<512, 256, 0, stream>>>(featT, wqk_bf, bq, bk, Qt, Kt, Ksum);
    v_mfma2<<<dim3(512, 2), 256, 0, stream>>>(featT, wv_bf, bv, (ushort_t*)d_out, Vsum);
    kv_outer<<<256, 256, 0, stream>>>(Kt, (const ushort_t*)d_out, matT);
    tailor_k<<<256, 256, 0, stream>>>(Qt, Ksum, tailor);
    final_mfma<<<dim3(2, 512), 256, 0, stream>>>(xb, Qt, matT, Vsum, tailor,
                                                 scale, shift, gamma_p,
                                                 (float*)d_out);
}